// Round 1
// 1240.705 us; speedup vs baseline: 1.0101x; 1.0101x over previous
//
#include <hip/hip_runtime.h>

typedef unsigned short u16;
typedef unsigned int   u32;
typedef __attribute__((ext_vector_type(8))) short bf16x8;
typedef __attribute__((ext_vector_type(4))) float f32x4;
typedef __attribute__((ext_vector_type(4))) u16  u16x4;

#define E_EDGES 262144
#define T_TRIP  2097152
#define XS   136   // LDS row stride (shorts) for K=128 tiles (+8 pad)
#define XS64 72    // LDS row stride for K=64 tiles

// bf16 transposed-weight offsets in workspace (elements). Layout: Wt[n*K + k]
#define OFF_KJ   0
#define OFF_JI   16384
#define OFF_DOWN 32768
#define OFF_UP   40960
#define OFF_RB0  49152
#define OFF_RB1  65536
#define OFF_FIN  81920
#define OFF_A00  98304
#define OFF_A01  114688
#define OFF_A10  131072
#define OFF_A11  147456
#define OFF_W2T  163840   // W_rbf2 transposed [128][8]

__device__ __forceinline__ u16 f2b(float f) {
  u32 u = __float_as_uint(f);
  u += 0x7FFFu + ((u >> 16) & 1u);          // RNE
  return (u16)(u >> 16);
}
__device__ __forceinline__ float b2f(u16 h) { return __uint_as_float(((u32)h) << 16); }
__device__ __forceinline__ float swishf(float x) {
  return x * __builtin_amdgcn_rcpf(1.0f + __expf(-x));
}

// ---------------- MFMA stage: C[128xN] += X[128xK] * W^T[NxK] -------------
// A-frag: lane holds A[m=lane&15][k=q*8+j]; B-frag: B[n=lane&15][k=q*8+j];
// C/D: col=lane&15, row=(lane>>4)*4+reg   (gfx950-verified layouts)
template<int NRT, int NCT, int NK>
__device__ __forceinline__ void mfma_stage(const u16* __restrict__ Xl, int xstr,
                                           const u16* __restrict__ Wl, int wstr,
                                           int r0, int c0, f32x4* acc, int m, int q) {
#pragma unroll
  for (int k = 0; k < NK; ++k) {
    bf16x8 a[NRT], b[NCT];
#pragma unroll
    for (int rt = 0; rt < NRT; ++rt)
      a[rt] = *(const bf16x8*)&Xl[(r0 + rt * 16 + m) * xstr + k * 32 + q * 8];
#pragma unroll
    for (int ct = 0; ct < NCT; ++ct)
      b[ct] = *(const bf16x8*)&Wl[(c0 + ct * 16 + m) * wstr + k * 32 + q * 8];
#pragma unroll
    for (int rt = 0; rt < NRT; ++rt)
#pragma unroll
      for (int ct = 0; ct < NCT; ++ct)
        acc[rt * NCT + ct] = __builtin_amdgcn_mfma_f32_16x16x32_bf16(
            a[rt], b[ct], acc[rt * NCT + ct], 0, 0, 0);
  }
}

template<int K>
__device__ __forceinline__ void loadW(u16* Wl, int wstr, const u16* __restrict__ src,
                                      int rows, int tid) {
  const int CPR = K / 8;
  for (int i = tid; i < rows * CPR; i += 256) {
    int r = i / CPR, c = i - r * CPR;
    *(uint4*)&Wl[r * wstr + c * 8] = *(const uint4*)&src[(size_t)r * K + c * 8];
  }
}

__device__ __forceinline__ void load_bias(const float* __restrict__ b, int c0, int m, float* bv) {
#pragma unroll
  for (int ct = 0; ct < 4; ++ct) bv[ct] = b[c0 + ct * 16 + m];
}

// ---------------- weight prep: fp32 -> bf16, transposed ----------------
struct WDesc  { const float* src; int K; int N; int dst; };
struct WDescs { WDesc d[12]; };

__global__ void prep_weights(WDescs W, u16* __restrict__ dst) {
  WDesc dd = W.d[blockIdx.y];
  int total = dd.K * dd.N;
  for (int i = blockIdx.x * 256 + threadIdx.x; i < total; i += 64 * 256) {
    int k = i / dd.N, n = i - k * dd.N;
    dst[dd.dst + n * dd.K + k] = f2b(dd.src[i]);
  }
}

// ---------------- kernel A: edge pre-stage ----------------
// m_ji = swish(X@W_ji + b_ji)                       -> global bf16 [E][128]
// S    = swish(X@W_kj + b_kj) * ((rbf@W1)@W2)       (gate via rank-8 MFMA)
// m_down = swish(S@W_down)                          -> global bf16 [E][64]
__global__ __launch_bounds__(256, 2) void kernelA(
    const float* __restrict__ m_input, const float* __restrict__ rbf,
    const float* __restrict__ b_kj, const float* __restrict__ b_ji,
    const float* __restrict__ W_rbf1, const u16* __restrict__ wts,
    u16* __restrict__ m_down, u16* __restrict__ m_ji) {
  __shared__ __align__(16) u16 Xa[128 * XS];
  __shared__ __align__(16) u16 Wt[128 * XS];
  __shared__ __align__(16) u16 u_l[128 * 8];
  __shared__ __align__(16) u16 w2t_l[128 * 8];
  __shared__ float rbf_s[128 * 6];

  const int tid = threadIdx.x;
  const int m = tid & 15, q = (tid >> 4) & 3, w = tid >> 6;
  const int r0 = (w >> 1) * 64, c0 = (w & 1) * 64;
  const int e0 = blockIdx.x * 128;

  // stage m_input tile -> Xa (bf16)
  for (int i = tid; i < 128 * 32; i += 256) {
    int r = i >> 5, c4 = i & 31;
    float4 v = ((const float4*)m_input)[(size_t)(e0 + r) * 32 + c4];
    u16x4 b; b.x = f2b(v.x); b.y = f2b(v.y); b.z = f2b(v.z); b.w = f2b(v.w);
    *(u16x4*)&Xa[r * XS + c4 * 4] = b;
  }
  for (int i = tid; i < 128 * 6; i += 256) rbf_s[i] = rbf[(size_t)e0 * 6 + i];
  for (int i = tid; i < 1024; i += 256) w2t_l[i] = wts[OFF_W2T + i];
  loadW<128>(Wt, XS, wts + OFF_JI, 128, tid);
  __syncthreads();

  // u = rbf @ W_rbf1  (bf16 into LDS)
  for (int v = tid; v < 1024; v += 256) {
    int t = v >> 3, b = v & 7;
    float s = 0.f;
#pragma unroll
    for (int j = 0; j < 6; ++j) s += rbf_s[t * 6 + j] * W_rbf1[j * 8 + b];
    u_l[v] = f2b(s);
  }

  f32x4 acc[16];
  // ---- stage JI ----
#pragma unroll
  for (int i = 0; i < 16; ++i) acc[i] = (f32x4){0.f, 0.f, 0.f, 0.f};
  mfma_stage<4, 4, 4>(Xa, XS, Wt, XS, r0, c0, acc, m, q);
  {
    float bv[4]; load_bias(b_ji, c0, m, bv);
#pragma unroll
    for (int rt = 0; rt < 4; ++rt)
#pragma unroll
      for (int ct = 0; ct < 4; ++ct)
#pragma unroll
        for (int rg = 0; rg < 4; ++rg) {
          int row = r0 + rt * 16 + q * 4 + rg, col = c0 + ct * 16 + m;
          m_ji[(size_t)(e0 + row) * 128 + col] = f2b(swishf(acc[rt * 4 + ct][rg] + bv[ct]));
        }
  }
  __syncthreads();               // Xa/Wt/u_l settled
  loadW<128>(Wt, XS, wts + OFF_KJ, 128, tid);
  __syncthreads();

  // ---- gate: G = U @ W2 (K=8 inside one 16x16x32 MFMA, q>0 lanes feed zeros) ----
  f32x4 gacc[16];
#pragma unroll
  for (int i = 0; i < 16; ++i) gacc[i] = (f32x4){0.f, 0.f, 0.f, 0.f};
  {
    bf16x8 zz = {0, 0, 0, 0, 0, 0, 0, 0};
    bf16x8 ua[4], wb[4];
#pragma unroll
    for (int rt = 0; rt < 4; ++rt) {
      ua[rt] = zz;
      if (q == 0) ua[rt] = *(const bf16x8*)&u_l[(r0 + rt * 16 + m) * 8];
    }
#pragma unroll
    for (int ct = 0; ct < 4; ++ct) {
      wb[ct] = zz;
      if (q == 0) wb[ct] = *(const bf16x8*)&w2t_l[(c0 + ct * 16 + m) * 8];
    }
#pragma unroll
    for (int rt = 0; rt < 4; ++rt)
#pragma unroll
      for (int ct = 0; ct < 4; ++ct)
        gacc[rt * 4 + ct] = __builtin_amdgcn_mfma_f32_16x16x32_bf16(
            ua[rt], wb[ct], gacc[rt * 4 + ct], 0, 0, 0);
  }
  // ---- stage KJ ----
#pragma unroll
  for (int i = 0; i < 16; ++i) acc[i] = (f32x4){0.f, 0.f, 0.f, 0.f};
  mfma_stage<4, 4, 4>(Xa, XS, Wt, XS, r0, c0, acc, m, q);
  __syncthreads();               // all Xa reads done before in-place overwrite
  {
    float bv[4]; load_bias(b_kj, c0, m, bv);
#pragma unroll
    for (int rt = 0; rt < 4; ++rt)
#pragma unroll
      for (int ct = 0; ct < 4; ++ct)
#pragma unroll
        for (int rg = 0; rg < 4; ++rg) {
          int row = r0 + rt * 16 + q * 4 + rg, col = c0 + ct * 16 + m;
          float v = swishf(acc[rt * 4 + ct][rg] + bv[ct]) * gacc[rt * 4 + ct][rg];
          Xa[row * XS + col] = f2b(v);
        }
  }
  loadW<128>(Wt, XS, wts + OFF_DOWN, 64, tid);
  __syncthreads();

  // ---- stage DOWN (N=64): each wave does rows [32w,32w+32) x cols [0,64) ----
  f32x4 acc2[8];
#pragma unroll
  for (int i = 0; i < 8; ++i) acc2[i] = (f32x4){0.f, 0.f, 0.f, 0.f};
  mfma_stage<2, 4, 4>(Xa, XS, Wt, XS, w * 32, 0, acc2, m, q);
#pragma unroll
  for (int rt = 0; rt < 2; ++rt)
#pragma unroll
    for (int ct = 0; ct < 4; ++ct)
#pragma unroll
      for (int rg = 0; rg < 4; ++rg) {
        int row = w * 32 + rt * 16 + q * 4 + rg, col = ct * 16 + m;
        m_down[(size_t)(e0 + row) * 64 + col] = f2b(swishf(acc2[rt * 4 + ct][rg]));
      }
}

// ---------------- kernel B: triplet gate + gather + atomic scatter ----------------
// Restructured: all 32 gather loads issue BEFORE any atomic, so the vmcnt FIFO
// never forces a wave to wait on an atomic acknowledgment (the old interleaved
// loop stalled ~8x per wave on atomic-ack round-trips).
__global__ __launch_bounds__(256, 4) void kernelB(
    const float* __restrict__ sbf, const int* __restrict__ expand,
    const int* __restrict__ reduce, const float* __restrict__ W_sbf1,
    const float* __restrict__ W_sbf2, const u16* __restrict__ m_down,
    float* __restrict__ agg) {
  __shared__ __align__(16) float sbf_s[128 * 42];
  __shared__ __align__(16) float u_s[128 * 8];
  __shared__ __align__(16) float w1_s[336];
  __shared__ int eidx[128];
  __shared__ int ridx[128];

  const int tid = threadIdx.x;
  const size_t t0 = (size_t)blockIdx.x * 128;
  // float4-vectorized staging: 128*42 floats = 1344 float4 (t0*42 % 4 == 0)
  {
    const float4* src = (const float4*)(sbf + t0 * 42);
    for (int i = tid; i < 1344; i += 256) ((float4*)sbf_s)[i] = src[i];
    for (int i = tid; i < 84; i += 256) ((float4*)w1_s)[i] = ((const float4*)W_sbf1)[i];
  }
  if (tid < 128) eidx[tid] = expand[t0 + tid];
  else           ridx[tid - 128] = reduce[t0 + tid - 128];
  __syncthreads();

  for (int v = tid; v < 1024; v += 256) {
    int t = v >> 3, b = v & 7;
    float s = 0.f;
#pragma unroll
    for (int j = 0; j < 42; ++j) s += sbf_s[t * 42 + j] * w1_s[j * 8 + b];
    u_s[v] = s;
  }
  __syncthreads();

  const int w = tid >> 6, lane = tid & 63;
  float w2[8];
#pragma unroll
  for (int b = 0; b < 8; ++b) w2[b] = W_sbf2[b * 64 + lane];

  // phase 1: all 32 gate values (broadcast ds_read_b128 pairs)
  float g[32];
#pragma unroll
  for (int i = 0; i < 32; ++i) {
    int t = w * 32 + i;
    float4 ua = *(const float4*)&u_s[t * 8];
    float4 ub = *(const float4*)&u_s[t * 8 + 4];
    g[i] = ua.x * w2[0] + ua.y * w2[1] + ua.z * w2[2] + ua.w * w2[3] +
           ub.x * w2[4] + ub.y * w2[5] + ub.z * w2[6] + ub.w * w2[7];
  }

  // phase 2: issue ALL gather loads (32 outstanding, no atomics in the FIFO yet)
  u16 mv[32];
#pragma unroll
  for (int i = 0; i < 32; ++i) {
    int e = eidx[w * 32 + i];
    mv[i] = m_down[(size_t)e * 64 + lane];
  }
  __builtin_amdgcn_sched_barrier(0);   // pin: no atomic may be hoisted above the loads

  // phase 3: fire-and-forget atomics; every vmcnt wait ahead of a use is
  // satisfied by (older) load completions, never by an atomic ack.
#pragma unroll
  for (int i = 0; i < 32; ++i) {
    int r = ridx[w * 32 + i];
    unsafeAtomicAdd(&agg[(size_t)r * 64 + lane], b2f(mv[i]) * g[i]);
  }
}

// ---------------- kernel C: fused up-projection + residual chain ----------------
__global__ __launch_bounds__(256, 2) void kernelC(
    const float* __restrict__ agg, const u16* __restrict__ m_ji,
    const float* __restrict__ m_input, const u16* __restrict__ wts,
    const float* __restrict__ b_res_b, const float* __restrict__ b_final,
    const float* __restrict__ b_res_a, float* __restrict__ out) {
  __shared__ __align__(16) u16 Xa[128 * XS];
  __shared__ __align__(16) u16 Wt[128 * XS];

  const int tid = threadIdx.x;
  const int m = tid & 15, q = (tid >> 4) & 3, w = tid >> 6;
  const int r0 = (w >> 1) * 64, c0 = (w & 1) * 64;
  const int e0 = blockIdx.x * 128;

  // agg fp32 [E][64] -> Xa bf16 (stride XS64)
  for (int i = tid; i < 128 * 16; i += 256) {
    int r = i >> 4, c4 = i & 15;
    float4 v = ((const float4*)agg)[(size_t)(e0 + r) * 16 + c4];
    u16x4 b; b.x = f2b(v.x); b.y = f2b(v.y); b.z = f2b(v.z); b.w = f2b(v.w);
    *(u16x4*)&Xa[r * XS64 + c4 * 4] = b;
  }
  loadW<64>(Wt, XS64, wts + OFF_UP, 128, tid);
  __syncthreads();

  f32x4 acc[16];
  u32 carry[32];
  float car3[64];

#define REINIT() _Pragma("unroll") for (int i = 0; i < 16; ++i) acc[i] = (f32x4){0.f,0.f,0.f,0.f}
#define EPI_BEGIN \
  _Pragma("unroll") for (int rt = 0; rt < 4; ++rt) \
  _Pragma("unroll") for (int ct = 0; ct < 4; ++ct) \
  _Pragma("unroll") for (int rg = 0; rg < 4; ++rg) { \
    int row = r0 + rt * 16 + q * 4 + rg, col = c0 + ct * 16 + m; \
    int ti = rt * 4 + ct; (void)row; (void)col; \
    float v = acc[ti][rg];
#define EPI_END }

  // ---- C1: m0 = swish(agg@W_up) + m_ji ; carry m0 ----
  REINIT();
  mfma_stage<4, 4, 2>(Xa, XS64, Wt, XS64, r0, c0, acc, m, q);
  __syncthreads();
  EPI_BEGIN
    v = swishf(v) + b2f(m_ji[(size_t)(e0 + row) * 128 + col]);
    acc[ti][rg] = v;
    Xa[row * XS + col] = f2b(v);
    if (rg == 3) {
      carry[ti * 2 + 0] = (u32)f2b(acc[ti][0]) | ((u32)f2b(acc[ti][1]) << 16);
      carry[ti * 2 + 1] = (u32)f2b(acc[ti][2]) | ((u32)f2b(acc[ti][3]) << 16);
    }
  EPI_END
  loadW<128>(Wt, XS, wts + OFF_RB0, 128, tid);
  __syncthreads();

  // ---- C2: r = swish(m0@Wb0 + bb0) ----
  REINIT();
  mfma_stage<4, 4, 4>(Xa, XS, Wt, XS, r0, c0, acc, m, q);
  __syncthreads();
  {
    float bv[4]; load_bias(b_res_b, c0, m, bv);
    EPI_BEGIN
      Xa[row * XS + col] = f2b(swishf(v + bv[ct]));
    EPI_END
  }
  loadW<128>(Wt, XS, wts + OFF_RB1, 128, tid);
  __syncthreads();

  // ---- C3: m1 = m0 + swish(r@Wb1 + bb1) ----
  REINIT();
  mfma_stage<4, 4, 4>(Xa, XS, Wt, XS, r0, c0, acc, m, q);
  __syncthreads();
  {
    float bv[4]; load_bias(b_res_b + 128, c0, m, bv);
    EPI_BEGIN
      u32 cw = carry[ti * 2 + (rg >> 1)];
      float base = b2f((u16)((rg & 1) ? (cw >> 16) : (cw & 0xffff)));
      Xa[row * XS + col] = f2b(swishf(v + bv[ct]) + base);
    EPI_END
  }
  loadW<128>(Wt, XS, wts + OFF_FIN, 128, tid);
  __syncthreads();

  // ---- C4: m2 = swish(m1@Wf + bf) + m_input ; carry m2 ----
  REINIT();
  mfma_stage<4, 4, 4>(Xa, XS, Wt, XS, r0, c0, acc, m, q);
  __syncthreads();
  {
    float bv[4]; load_bias(b_final, c0, m, bv);
    EPI_BEGIN
      v = swishf(v + bv[ct]) + m_input[(size_t)(e0 + row) * 128 + col];
      acc[ti][rg] = v;
      Xa[row * XS + col] = f2b(v);
      if (rg == 3) {
        carry[ti * 2 + 0] = (u32)f2b(acc[ti][0]) | ((u32)f2b(acc[ti][1]) << 16);
        carry[ti * 2 + 1] = (u32)f2b(acc[ti][2]) | ((u32)f2b(acc[ti][3]) << 16);
      }
    EPI_END
  }
  loadW<128>(Wt, XS, wts + OFF_A00, 128, tid);
  __syncthreads();

  // ---- C5: r = swish(m2@Wa00 + ba00) ----
  REINIT();
  mfma_stage<4, 4, 4>(Xa, XS, Wt, XS, r0, c0, acc, m, q);
  __syncthreads();
  {
    float bv[4]; load_bias(b_res_a, c0, m, bv);
    EPI_BEGIN
      Xa[row * XS + col] = f2b(swishf(v + bv[ct]));
    EPI_END
  }
  loadW<128>(Wt, XS, wts + OFF_A01, 128, tid);
  __syncthreads();

  // ---- C6: m3 = m2 + swish(r@Wa01 + ba01) ; carry m3 in fp32 ----
  REINIT();
  mfma_stage<4, 4, 4>(Xa, XS, Wt, XS, r0, c0, acc, m, q);
  __syncthreads();
  {
    float bv[4]; load_bias(b_res_a + 128, c0, m, bv);
    EPI_BEGIN
      u32 cw = carry[ti * 2 + (rg >> 1)];
      float base = b2f((u16)((rg & 1) ? (cw >> 16) : (cw & 0xffff)));
      v = swishf(v + bv[ct]) + base;
      car3[ti * 4 + rg] = v;
      Xa[row * XS + col] = f2b(v);
    EPI_END
  }
  loadW<128>(Wt, XS, wts + OFF_A10, 128, tid);
  __syncthreads();

  // ---- C7: r = swish(m3@Wa10 + ba10) ----
  REINIT();
  mfma_stage<4, 4, 4>(Xa, XS, Wt, XS, r0, c0, acc, m, q);
  __syncthreads();
  {
    float bv[4]; load_bias(b_res_a + 256, c0, m, bv);
    EPI_BEGIN
      Xa[row * XS + col] = f2b(swishf(v + bv[ct]));
    EPI_END
  }
  loadW<128>(Wt, XS, wts + OFF_A11, 128, tid);
  __syncthreads();

  // ---- C8: out = m3 + swish(r@Wa11 + ba11) ----
  REINIT();
  mfma_stage<4, 4, 4>(Xa, XS, Wt, XS, r0, c0, acc, m, q);
  {
    float bv[4]; load_bias(b_res_a + 384, c0, m, bv);
    EPI_BEGIN
      out[(size_t)(e0 + row) * 128 + col] = swishf(v + bv[ct]) + car3[ti * 4 + rg];
    EPI_END
  }
#undef REINIT
#undef EPI_BEGIN
#undef EPI_END
}

extern "C" void kernel_launch(void* const* d_in, const int* in_sizes, int n_in,
                              void* d_out, int out_size, void* d_ws, size_t ws_size,
                              hipStream_t stream) {
  (void)in_sizes; (void)n_in; (void)out_size; (void)ws_size;
  const float* m_input = (const float*)d_in[0];
  const float* rbf     = (const float*)d_in[1];
  const float* sbf     = (const float*)d_in[2];
  const int*   expand  = (const int*)d_in[3];
  const int*   reduce  = (const int*)d_in[4];
  const float* W_kj    = (const float*)d_in[5];
  const float* b_kj    = (const float*)d_in[6];
  const float* W_rbf1  = (const float*)d_in[7];
  const float* W_rbf2  = (const float*)d_in[8];
  const float* W_sbf1  = (const float*)d_in[9];
  const float* W_sbf2  = (const float*)d_in[10];
  const float* W_down  = (const float*)d_in[11];
  const float* W_up    = (const float*)d_in[12];
  const float* W_ji    = (const float*)d_in[13];
  const float* b_ji    = (const float*)d_in[14];
  const float* W_res_b = (const float*)d_in[15];
  const float* b_res_b = (const float*)d_in[16];
  const float* W_final = (const float*)d_in[17];
  const float* b_final = (const float*)d_in[18];
  const float* W_res_a = (const float*)d_in[19];
  const float* b_res_a = (const float*)d_in[20];

  char* ws = (char*)d_ws;
  u16*   wts    = (u16*)ws;
  u16*   m_down = (u16*)(ws + (1u << 20));
  u16*   m_ji   = (u16*)(ws + (1u << 20) + (size_t)E_EDGES * 64 * 2);
  float* agg    = (float*)(ws + (1u << 20) + (size_t)E_EDGES * 64 * 2 + (size_t)E_EDGES * 128 * 2);

  WDescs wd;
  wd.d[0]  = {W_kj,            128, 128, OFF_KJ};
  wd.d[1]  = {W_ji,            128, 128, OFF_JI};
  wd.d[2]  = {W_down,          128,  64, OFF_DOWN};
  wd.d[3]  = {W_up,             64, 128, OFF_UP};
  wd.d[4]  = {W_res_b,         128, 128, OFF_RB0};
  wd.d[5]  = {W_res_b + 16384, 128, 128, OFF_RB1};
  wd.d[6]  = {W_final,         128, 128, OFF_FIN};
  wd.d[7]  = {W_res_a,         128, 128, OFF_A00};
  wd.d[8]  = {W_res_a + 16384, 128, 128, OFF_A01};
  wd.d[9]  = {W_res_a + 32768, 128, 128, OFF_A10};
  wd.d[10] = {W_res_a + 49152, 128, 128, OFF_A11};
  wd.d[11] = {W_rbf2,            8, 128, OFF_W2T};

  prep_weights<<<dim3(64, 12), 256, 0, stream>>>(wd, wts);
  hipMemsetAsync(agg, 0, (size_t)E_EDGES * 64 * 4, stream);
  kernelA<<<E_EDGES / 128, 256, 0, stream>>>(m_input, rbf, b_kj, b_ji, W_rbf1, wts, m_down, m_ji);
  kernelB<<<T_TRIP / 128, 256, 0, stream>>>(sbf, expand, reduce, W_sbf1, W_sbf2, m_down, agg);
  kernelC<<<E_EDGES / 128, 256, 0, stream>>>(agg, m_ji, m_input, wts, b_res_b, b_final, b_res_a,
                                             (float*)d_out);
}